// Round 7
// baseline (157.552 us; speedup 1.0000x reference)
//
#include <hip/hip_runtime.h>

#define NIN  128
#define NOUT 128
#define NN   256   // N
#define BB   4     // batch

typedef float f4 __attribute__((ext_vector_type(4)));

// ---------------- Kernel A: u{i,j}[b,o,j] = sum_c W{i,j}[o,c] * node[b,c,j] ----------------
// 512 blocks (one per b,o), 256 threads = (j-quad tq, channel-group g of 32).
// Each thread: 32 coalesced 16B node loads + f4 FMAs; LDS tree-reduce; f4 store.
__global__ __launch_bounds__(256) void precompute_u(
    const float* __restrict__ node,  // [B,NIN,N]
    const float* __restrict__ Wi,    // [NOUT,NIN]
    const float* __restrict__ Wj,    // [NOUT,NIN]
    float* __restrict__ ui,          // [B*NOUT, N]
    float* __restrict__ uj)          // [B*NOUT, N]
{
    __shared__ f4 part[2][4][64];    // [sel][group][j-quad]  8 KiB

    const int bo = blockIdx.x;
    const int b  = bo >> 7;
    const int o  = bo & (NOUT - 1);
    const int t  = threadIdx.x;
    const int tq = t & 63;           // j-quad: columns 4*tq..4*tq+3
    const int g  = t >> 6;           // channel group: c in [32g, 32g+32)

    const f4*    np4 = (const f4*)node + ((size_t)b * NIN + g * 32) * 64 + tq;
    const float* wi  = Wi + o * NIN + g * 32;   // block-uniform -> scalar loads
    const float* wj  = Wj + o * NIN + g * 32;

    f4 ai = {0.f, 0.f, 0.f, 0.f};
    f4 aj = {0.f, 0.f, 0.f, 0.f};
    #pragma unroll 8
    for (int c = 0; c < 32; ++c) {
        const f4 n = np4[(size_t)c * 64];       // 1 KiB/wave, coalesced
        ai += wi[c] * n;
        aj += wj[c] * n;
    }
    part[0][g][tq] = ai;
    part[1][g][tq] = aj;
    __syncthreads();

    if (t < 128) {
        const int q   = t & 63;
        const int sel = t >> 6;
        const f4 s = part[sel][0][q] + part[sel][1][q]
                   + part[sel][2][q] + part[sel][3][q];
        *(f4*)&(sel ? uj : ui)[bo * NN + (q << 2)] = s;
    }
}

// ---------------- Kernel B: out[b,o,i,j] = adj[b,i,j] * (i==j ? ui[j] : uj[j]) -------------
// R2's best-measured shape: 4096 blocks ((b,o) x 8 chunks of 32 rows), 256 threads.
// Nontemporal stores: out is write-once -> write-around L2, keep adj resident.
__global__ __launch_bounds__(256) void stream_out(
    const float* __restrict__ adj,   // [B,1,N,N]
    const float* __restrict__ ui,    // [B*NOUT, N]
    const float* __restrict__ uj,    // [B*NOUT, N]
    float* __restrict__ out)         // [B,NOUT,N,N]
{
    const int blk = blockIdx.x;
    const int bo  = blk >> 3;
    const int rc  = blk & 7;          // 32-row chunk
    const int b   = bo >> 7;
    const int t   = threadIdx.x;
    const int jb  = (t & 63) << 2;    // base column (fixed per thread)
    const int rr  = t >> 6;           // 0..3

    const f4 vj = *(const f4*)&uj[bo * NN + jb];   // hoisted off-diagonal values
    const float* uip  = ui + bo * NN;
    const float* adjb = adj + (size_t)b * (NN * NN);
    float*       outp = out + (size_t)bo * (NN * NN);

    const int i0 = (rc << 5) + rr;
    #pragma unroll
    for (int r = 0; r < 8; ++r) {
        const int i = i0 + (r << 2);
        const float s_ii = uip[i];                   // same addr across wave -> broadcast
        const f4 a = *(const f4*)&adjb[i * NN + jb];
        f4 v;
        v.x = (i == jb + 0) ? s_ii : vj.x;
        v.y = (i == jb + 1) ? s_ii : vj.y;
        v.z = (i == jb + 2) ? s_ii : vj.z;
        v.w = (i == jb + 3) ? s_ii : vj.w;
        const f4 rs = a * v;
        __builtin_nontemporal_store(rs, (f4*)&outp[i * NN + jb]);  // 1 KiB/wave row
    }
}

// ---------------- Fallback (ws too small): fused kernel ----------------------------------
__global__ __launch_bounds__(256) void nodeconv_fused(
    const float* __restrict__ adj, const float* __restrict__ node,
    const float* __restrict__ Wi, const float* __restrict__ Wj,
    float* __restrict__ out)
{
    __shared__ float si[NN];
    __shared__ float sj[NN];
    const int bo = blockIdx.x;
    const int b  = bo >> 7;
    const int o  = bo & (NOUT - 1);
    const int t  = threadIdx.x;
    {
        const float* np_ = node + (size_t)(b * NIN) * NN + t;
        const float* wi  = Wi + o * NIN;
        const float* wj  = Wj + o * NIN;
        float ai = 0.f, aj = 0.f;
        #pragma unroll 8
        for (int c = 0; c < NIN; ++c) {
            const float n = np_[(size_t)c * NN];
            ai += wi[c] * n;
            aj += wj[c] * n;
        }
        si[t] = ai;
        sj[t] = aj;
    }
    __syncthreads();
    const int jb   = (t & 63) << 2;
    const int rrow = t >> 6;
    const f4 vj = *(const f4*)&sj[jb];
    const float* adjb = adj + (size_t)b * (NN * NN);
    float*       outp = out + (size_t)bo * (NN * NN);
    #pragma unroll 4
    for (int r = 0; r < 64; ++r) {
        const int i = (r << 2) + rrow;
        const float s_ii = si[i];
        const f4 a = *(const f4*)&adjb[i * NN + jb];
        f4 v;
        v.x = (i == jb + 0) ? s_ii : vj.x;
        v.y = (i == jb + 1) ? s_ii : vj.y;
        v.z = (i == jb + 2) ? s_ii : vj.z;
        v.w = (i == jb + 3) ? s_ii : vj.w;
        *(f4*)&outp[i * NN + jb] = a * v;
    }
}

extern "C" void kernel_launch(void* const* d_in, const int* in_sizes, int n_in,
                              void* d_out, int out_size, void* d_ws, size_t ws_size,
                              hipStream_t stream) {
    const float* adj  = (const float*)d_in[0];  // [4,1,256,256]
    const float* node = (const float*)d_in[1];  // [4,128,256]
    const float* Wi   = (const float*)d_in[2];  // [128,128]
    const float* Wj   = (const float*)d_in[3];  // [128,128]
    float* out = (float*)d_out;                 // [4,128,256,256]

    const size_t u_elems = (size_t)BB * NOUT * NN;          // 131072
    const size_t need    = 2 * u_elems * sizeof(float);     // 1 MiB

    if (ws_size >= need) {
        float* ui = (float*)d_ws;
        float* uj = ui + u_elems;
        precompute_u<<<dim3(BB * NOUT), dim3(256), 0, stream>>>(node, Wi, Wj, ui, uj);
        stream_out<<<dim3(BB * NOUT * 8), dim3(256), 0, stream>>>(adj, ui, uj, out);
    } else {
        nodeconv_fused<<<dim3(BB * NOUT), dim3(256), 0, stream>>>(adj, node, Wi, Wj, out);
    }
}